// Round 17
// baseline (224.196 us; speedup 1.0000x reference)
//
#include <hip/hip_runtime.h>
#include <math.h>

#define B_ 4
#define C_ 256
#define N_ 2048
#define H_ 8
#define D_ 64
#define BH_ 32
#define HC_ 2048
#define BN_EPS 1e-5f
#define SCL 1.2011224087864498f  // sqrt(log2(e)); P scaled so E' = log2(e)*E

typedef __attribute__((ext_vector_type(8))) short s8v;
typedef __attribute__((ext_vector_type(4))) short s4v;
typedef __attribute__((ext_vector_type(8))) _Float16 h8v;
typedef __attribute__((ext_vector_type(4))) _Float16 h4v;
typedef __attribute__((ext_vector_type(4))) float f32x4;

#define MFMA __builtin_amdgcn_mfma_f32_16x16x32_bf16
#define MFMAH __builtin_amdgcn_mfma_f32_16x16x32_f16

static __device__ __forceinline__ unsigned short f2b(float f) {
  union { float f; unsigned int i; } v; v.f = f;
  unsigned int r = v.i + 0x7FFFu + ((v.i >> 16) & 1u);
  return (unsigned short)(r >> 16);
}
static __device__ __forceinline__ float fexp2(float x) {
  float r;
  asm("v_exp_f32 %0, %1" : "=v"(r) : "v"(x));
  return r;
}
static __device__ __forceinline__ unsigned cvtpk(float lo, float hi) {
  unsigned r;
  asm("v_cvt_pk_bf16_f32 %0, %1, %2" : "=v"(r) : "v"(lo), "v"(hi));
  return r;
}
static __device__ __forceinline__ void gload16(const void* g, void* l) {
  __builtin_amdgcn_global_load_lds(
      (const __attribute__((address_space(1))) unsigned int*)g,
      (__attribute__((address_space(3))) unsigned int*)l, 16, 0, 0);
}

struct GP {
  const float *x, *w_qk, *w_v, *b_v, *w_t, *b_t, *bn_g, *bn_b, *bn_m, *bn_v;
  const float *w_lin, *lbn_g, *lbn_b, *lbn_m, *lbn_v;
  _Float16 *PT, *xT, *wqk16, *wvh;
  short *HOT, *wtb, *wlinb, *Vb, *xmr;
  float *part, *shb, *nrm, *sh, *out;
};

// fused weight conversions: w_t->bf16, w_lin->bf16, w_v->fp16, w_qk->fp16
__global__ __launch_bounds__(256) void prep_k(GP p) {
  int u = blockIdx.x * 256 + threadIdx.x;
  if (u < 131072) {
    int i = u * 4;
    float4 v = *(const float4*)(p.w_t + i);
    s4v o = { (short)f2b(v.x), (short)f2b(v.y), (short)f2b(v.z), (short)f2b(v.w) };
    *(s4v*)(p.wtb + i) = o;
  } else if (u < 262144) {
    int i = (u - 131072) * 4;
    float4 v = *(const float4*)(p.w_lin + i);
    s4v o = { (short)f2b(v.x), (short)f2b(v.y), (short)f2b(v.z), (short)f2b(v.w) };
    *(s4v*)(p.wlinb + i) = o;
  } else if (u < 393216) {
    int i = (u - 262144) * 4;
    float4 v = *(const float4*)(p.w_v + i);
    h4v o = { (_Float16)v.x, (_Float16)v.y, (_Float16)v.z, (_Float16)v.w };
    *(h4v*)(p.wvh + i) = o;
  } else {
    int i = (u - 393216) * 4;
    float4 v = *(const float4*)(p.w_qk + i);
    h4v o = { (_Float16)v.x, (_Float16)v.y, (_Float16)v.z, (_Float16)v.w };
    *(h4v*)(p.wqk16 + i) = o;
  }
}

// x [B][C][N] fp32 -> xT [B][N][C] fp16
__global__ __launch_bounds__(256) void xcvt_k(const float* __restrict__ x,
                                              _Float16* __restrict__ xT) {
  const int n0 = blockIdx.x * 64, c0 = blockIdx.y * 64, b = blockIdx.z;
  const float* xb = x + (size_t)b * C_ * N_;
  __shared__ float sm[64][65];
  const int t = threadIdx.x;
#pragma unroll
  for (int i = 0; i < 4; ++i) {
    int idx = i * 256 + t;
    int c = idx >> 4, j = (idx & 15) * 4;
    float4 v = *(const float4*)(xb + (size_t)(c0 + c) * N_ + n0 + j);
    sm[j + 0][c] = v.x; sm[j + 1][c] = v.y; sm[j + 2][c] = v.z; sm[j + 3][c] = v.w;
  }
  __syncthreads();
#pragma unroll
  for (int i = 0; i < 2; ++i) {
    int idx = i * 256 + t;
    int n = idx >> 3, cg = (idx & 7) * 8;
    h8v o;
#pragma unroll
    for (int d = 0; d < 8; ++d) o[d] = (_Float16)sm[n][cg + d];
    *(h8v*)(xT + ((size_t)b * N_ + n0 + n) * C_ + c0 + cg) = o;
  }
}

// P = w_qk*x fp16 MFMA; writes SCALED fp16 PT [bh][N][D] + row sumsq nrm
__global__ __launch_bounds__(256, 2) void p_k(GP p) {
  const int t = threadIdx.x, wv = t >> 6, lane = t & 63;
  const int l15 = lane & 15, l4 = lane >> 4;
  const int n0 = blockIdx.x * 128;
  const int bh = blockIdx.y, b = bh / H_, h = bh % H_;
  const _Float16* Ag = p.wqk16 + h * D_ * C_;
  const _Float16* Bg = p.xT + (size_t)b * N_ * C_;
  __shared__ _Float16 As[64 * 64], Bs[128 * 64];
  __shared__ float Tr[128 * 65];
  f32x4 acc[4][2] = {};
  for (int kc = 0; kc < 256; kc += 64) {
    __syncthreads();
#pragma unroll
    for (int i = 0; i < 2; ++i) {
      int idx = i * 256 + t;
      int row = idx >> 3, offl = (idx & 7) * 16;
      gload16((const char*)(Ag + (size_t)row * C_ + kc) + (offl ^ ((row & 7) << 4)),
              (char*)As + idx * 16);
    }
#pragma unroll
    for (int i = 0; i < 4; ++i) {
      int idx = i * 256 + t;
      int row = idx >> 3, offl = (idx & 7) * 16;
      gload16((const char*)(Bg + (size_t)(n0 + row) * C_ + kc) + (offl ^ ((row & 7) << 4)),
              (char*)Bs + idx * 16);
    }
    __syncthreads();
    h8v ad[4][2], bn[2][2];
#pragma unroll
    for (int d = 0; d < 4; ++d)
#pragma unroll
      for (int ks = 0; ks < 2; ++ks) {
        int row = d * 16 + l15;
        ad[d][ks] = *(const h8v*)((const char*)As + row * 128 + ((ks * 64 + l4 * 16) ^ ((row & 7) << 4)));
      }
#pragma unroll
    for (int nb = 0; nb < 2; ++nb)
#pragma unroll
      for (int ks = 0; ks < 2; ++ks) {
        int row = wv * 32 + nb * 16 + l15;
        bn[nb][ks] = *(const h8v*)((const char*)Bs + row * 128 + ((ks * 64 + l4 * 16) ^ ((row & 7) << 4)));
      }
#pragma unroll
    for (int d = 0; d < 4; ++d)
#pragma unroll
      for (int nb = 0; nb < 2; ++nb) {
        acc[d][nb] = MFMAH(ad[d][0], bn[nb][0], acc[d][nb], 0, 0, 0);
        acc[d][nb] = MFMAH(ad[d][1], bn[nb][1], acc[d][nb], 0, 0, 0);
      }
  }
  __syncthreads();
#pragma unroll
  for (int d = 0; d < 4; ++d)
#pragma unroll
    for (int nb = 0; nb < 2; ++nb)
#pragma unroll
      for (int r = 0; r < 4; ++r) {
        int n_l = wv * 32 + nb * 16 + l15;
        int dd = d * 16 + l4 * 4 + r;
        Tr[n_l * 65 + dd] = acc[d][nb][r];
      }
  __syncthreads();
  _Float16* Pf = p.PT + ((size_t)bh * N_ + n0) * D_;
  float* nz = p.nrm + (size_t)bh * N_;
#pragma unroll
  for (int i = 0; i < 4; ++i) {
    int idx = i * 256 + t;
    int n = idx >> 3, dg = (idx & 7) * 8;
    h8v hv;
    float ssq = 0.f;
#pragma unroll
    for (int j = 0; j < 8; ++j) {
      float v = Tr[n * 65 + dg + j] * SCL;
      ssq = fmaf(v, v, ssq);
      hv[j] = (_Float16)v;
    }
    *(h8v*)(Pf + (size_t)n * D_ + dg) = hv;
    ssq += __shfl_xor(ssq, 1, 64);
    ssq += __shfl_xor(ssq, 2, 64);
    ssq += __shfl_xor(ssq, 4, 64);
    if ((t & 7) == 0) nz[n0 + n] = ssq;
  }
}

// per z: M' = max ||P'||; sh[n] = ||P'_n|| * M'  (upper bound on E' row max)
__global__ __launch_bounds__(256) void shift_k(const float* __restrict__ nrm,
                                               float* __restrict__ sh) {
  const int z = blockIdx.x, t = threadIdx.x;
  const float* nz = nrm + (size_t)z * N_;
  float loc[8];
  float mx = 0.f;
#pragma unroll
  for (int i = 0; i < 8; ++i) {
    loc[i] = nz[i * 256 + t];
    mx = fmaxf(mx, loc[i]);
  }
  for (int o = 32; o; o >>= 1) mx = fmaxf(mx, __shfl_xor(mx, o, 64));
  __shared__ float sb[4];
  if ((t & 63) == 0) sb[t >> 6] = mx;
  __syncthreads();
  float M = sqrtf(fmaxf(fmaxf(sb[0], sb[1]), fmaxf(sb[2], sb[3])));
#pragma unroll
  for (int i = 0; i < 8; ++i)
    sh[(size_t)z * N_ + i * 256 + t] = sqrtf(loc[i]) * M;
}

// pass A (symmetric, shifted, fp16): upper-tri 128x128 tiles, exp2(E'-sh) row+col sums
__global__ __launch_bounds__(256, 4) void passa_k(GP p) {
  const int t = threadIdx.x, wv = t >> 6, lane = t & 63;
  const int l15 = lane & 15, l4 = lane >> 4;
  const int wr = wv >> 1, wc = wv & 1;
  const int z = blockIdx.x;
  int idx = blockIdx.y;
  int ti = 0;
  while (idx >= 16 - ti) { idx -= 16 - ti; ++ti; }
  const int tj = ti + idx;
  const int r0 = ti * 128, c0 = tj * 128;
  const _Float16* Pz = p.PT + (size_t)z * N_ * D_;
  const float* shz = p.sh + (size_t)z * N_;
  __shared__ short RH[8192], CH[8192];
  __shared__ float rbuf[2][2][64], cbuf[2][2][64];
#pragma unroll
  for (int i = 0; i < 4; ++i) {
    int c2 = i * 256 + t;
    int row = c2 >> 3, offl = (c2 & 7) * 16;
    int so = offl ^ ((row & 7) << 4);
    gload16((const char*)(Pz + (size_t)(r0 + row) * D_) + so, (char*)RH + c2 * 16);
    if (ti != tj)
      gload16((const char*)(Pz + (size_t)(c0 + row) * D_) + so, (char*)CH + c2 * 16);
  }
  __syncthreads();
  const char* BHp = (ti == tj) ? (const char*)RH : (const char*)CH;

  h8v bh4[4][2];
  float shc[4];
#pragma unroll
  for (int nf = 0; nf < 4; ++nf) {
#pragma unroll
    for (int ks = 0; ks < 2; ++ks) {
      int row = wc * 64 + nf * 16 + l15;
      int byte = row * 128 + ((ks * 64 + l4 * 16) ^ ((row & 7) << 4));
      bh4[nf][ks] = *(const h8v*)(BHp + byte);
    }
    shc[nf] = shz[c0 + wc * 64 + nf * 16 + l15];
  }
  float rowp[4][4] = {};
  float colp[4] = {};
#pragma unroll
  for (int mf = 0; mf < 4; ++mf) {
    h8v ah[2];
#pragma unroll
    for (int ks = 0; ks < 2; ++ks) {
      int row = wr * 64 + mf * 16 + l15;
      int byte = row * 128 + ((ks * 64 + l4 * 16) ^ ((row & 7) << 4));
      ah[ks] = *(const h8v*)((const char*)RH + byte);
    }
    f32x4 shr = *(const f32x4*)(shz + r0 + wr * 64 + mf * 16 + l4 * 4);
#pragma unroll
    for (int nf = 0; nf < 4; ++nf) {
      f32x4 s = {};
      s = MFMAH(ah[0], bh4[nf][0], s, 0, 0, 0);
      s = MFMAH(ah[1], bh4[nf][1], s, 0, 0, 0);
      rowp[mf][0] += fexp2(s[0] - shr[0]);
      rowp[mf][1] += fexp2(s[1] - shr[1]);
      rowp[mf][2] += fexp2(s[2] - shr[2]);
      rowp[mf][3] += fexp2(s[3] - shr[3]);
      if (ti != tj)
        colp[nf] += fexp2(s[0] - shc[nf]) + fexp2(s[1] - shc[nf]) +
                    fexp2(s[2] - shc[nf]) + fexp2(s[3] - shc[nf]);
    }
  }
#pragma unroll
  for (int mf = 0; mf < 4; ++mf)
#pragma unroll
    for (int r = 0; r < 4; ++r) {
      float v = rowp[mf][r];
      v += __shfl_xor(v, 1, 64); v += __shfl_xor(v, 2, 64);
      v += __shfl_xor(v, 4, 64); v += __shfl_xor(v, 8, 64);
      rowp[mf][r] = v;
    }
#pragma unroll
  for (int nf = 0; nf < 4; ++nf) {
    float v = colp[nf];
    v += __shfl_xor(v, 16, 64); v += __shfl_xor(v, 32, 64);
    colp[nf] = v;
  }
  if (l15 == 0)
#pragma unroll
    for (int mf = 0; mf < 4; ++mf)
#pragma unroll
      for (int r = 0; r < 4; ++r)
        rbuf[wr][wc][mf * 16 + l4 * 4 + r] = rowp[mf][r];
  if (l4 == 0)
#pragma unroll
    for (int nf = 0; nf < 4; ++nf)
      cbuf[wc][wr][nf * 16 + l15] = colp[nf];
  __syncthreads();
  if (t < 128) {
    float v = rbuf[t >> 6][0][t & 63] + rbuf[t >> 6][1][t & 63];
    p.part[((size_t)z * 16 + tj) * N_ + r0 + t] = v;
  } else if (ti != tj) {
    int u = t - 128;
    float v = cbuf[u >> 6][0][u & 63] + cbuf[u >> 6][1][u & 63];
    p.part[((size_t)z * 16 + ti) * N_ + c0 + u] = v;
  }
}

// shb[z][n] = sh[z][n] + log2( sum_j part[z][j][n] )
__global__ __launch_bounds__(256) void shbred_k(const float* __restrict__ part,
                                                const float* __restrict__ sh,
                                                float* __restrict__ shb) {
  int i = blockIdx.x * 256 + threadIdx.x;
  int z = i >> 11, n = i & 2047;
  const float* pz = part + ((size_t)z * 16) * N_ + n;
  float s = 0.f;
#pragma unroll
  for (int j = 0; j < 16; ++j) s += pz[(size_t)j * N_];
  shb[i] = sh[i] + __log2f(s);
}

// pass B: fused exp2(s - shb) + PV + colsum renorm; 128-wide m tile
// steady-state pipeline: between barriers run PV(it) interleaved with QK(it+1)
// (disjoint AT buffers); same counted-vmcnt fence discipline as the 104us config
__global__ __launch_bounds__(256, 2) void passb_k(GP p) {
  const int t = threadIdx.x, wv = t >> 6, lane = t & 63;
  const int l15 = lane & 15, l4 = lane >> 4;
  const int z = blockIdx.x, b = z / H_;
  const int m0 = blockIdx.y * 128;
  const _Float16* Pz = p.PT + (size_t)z * N_ * D_;
  const short* Vz = p.Vb + (size_t)z * C_ * N_;
  const float* shbz = p.shb + (size_t)z * N_;

  __shared__ char smem[57856];
  // [0,16384): Pn[2] 8192B; [16384,49152): AT[2] 16384B; [49152,49664): cs; [49664,57856): shb
  float* cs_sm = (float*)(smem + 49152);
  float* shs = (float*)(smem + 49664);

  // B-operand (Pm): 2 fragments per wave
  h8v bm[2][2];
#pragma unroll
  for (int mf = 0; mf < 2; ++mf)
#pragma unroll
    for (int ks = 0; ks < 2; ++ks)
      bm[mf][ks] = *(const h8v*)(Pz + (size_t)(m0 + wv * 32 + mf * 16 + l15) * D_ + ks * 32 + l4 * 8);

  s8v va[4][2];
  f32x4 racc[4][8] = {};
  float csa0 = 0.f, csa1 = 0.f;

#define STAGE_PN(n0v, bufbyte) do { \
    _Pragma("unroll") \
    for (int i_ = 0; i_ < 2; ++i_) { \
      int sl_ = i_ * 256 + t; \
      int rw_ = sl_ >> 3, of_ = (sl_ & 7) * 16; \
      gload16((const char*)(Pz + (size_t)((n0v) + rw_) * D_) + (of_ ^ ((rw_ & 7) << 4)), \
              smem + (bufbyte) + sl_ * 16); \
    } \
  } while (0)
#define ISSUE_V(n0v) do { \
    _Pragma("unroll") \
    for (int eb = 0; eb < 4; ++eb) { \
      const short* vr_ = Vz + (size_t)(wv * 64 + eb * 16 + l15) * N_ + (n0v) + l4 * 8; \
      va[eb][0] = *(const s8v*)vr_; \
      va[eb][1] = *(const s8v*)(vr_ + 32); \
    } \
  } while (0)
// QK phase for n-tile jj: reads Pn[jj&1], writes AT[jj&1]
#define QK_PHASE(jj) do { \
    const int n0_ = (jj) * 64; \
    const char* PH_ = smem + ((jj) & 1) * 8192; \
    char* AT_ = smem + 16384 + ((jj) & 1) * 16384; \
    _Pragma("unroll") \
    for (int nb = 0; nb < 4; ++nb) { \
      int rowb = nb * 16 + l15; \
      int sw = (rowb & 7) << 4; \
      h8v an0 = *(const h8v*)(PH_ + rowb * 128 + ((l4 * 16) ^ sw)); \
      h8v an1 = *(const h8v*)(PH_ + rowb * 128 + ((64 + l4 * 16) ^ sw)); \
      f32x4 s0 = {}, s1 = {}; \
      s0 = MFMAH(an0, bm[0][0], s0, 0, 0, 0); \
      s0 = MFMAH(an1, bm[0][1], s0, 0, 0, 0); \
      s1 = MFMAH(an0, bm[1][0], s1, 0, 0, 0); \
      s1 = MFMAH(an1, bm[1][1], s1, 0, 0, 0); \
      f32x4 sb4 = *(const f32x4*)(shs + n0_ + nb * 16 + l4 * 4); \
      float a0 = fexp2(s0[0] - sb4[0]); \
      float a1 = fexp2(s0[1] - sb4[1]); \
      float a2 = fexp2(s0[2] - sb4[2]); \
      float a3 = fexp2(s0[3] - sb4[3]); \
      float c0 = fexp2(s1[0] - sb4[0]); \
      float c1 = fexp2(s1[1] - sb4[1]); \
      float c2 = fexp2(s1[2] - sb4[2]); \
      float c3 = fexp2(s1[3] - sb4[3]); \
      csa0 += (a0 + a1) + (a2 + a3); \
      csa1 += (c0 + c1) + (c2 + c3); \
      uint2 pk0 = { cvtpk(a0, a1), cvtpk(a2, a3) }; \
      uint2 pk1 = { cvtpk(c0, c1), cvtpk(c2, c3) }; \
      int swm = (l15 & 7) << 4; \
      int cb = (nb * 32 + l4 * 8); \
      *(uint2*)(AT_ + (wv * 32 + l15) * 128 + (cb ^ swm)) = pk0; \
      *(uint2*)(AT_ + (wv * 32 + 16 + l15) * 128 + (cb ^ swm)) = pk1; \
    } \
  } while (0)
// PV phase for n-tile jj: reads AT[jj&1] + va (V tile jj)
#define PV_PHASE(jj) do { \
    char* AT_ = smem + 16384 + ((jj) & 1) * 16384; \
    _Pragma("unroll") \
    for (int mb = 0; mb < 8; ++mb) { \
      int rowb = mb * 16 + l15; \
      int sw = (rowb & 7) << 4; \
      s8v at0 = *(const s8v*)(AT_ + rowb * 128 + ((l4 * 16) ^ sw)); \
      s8v at1 = *(const s8v*)(AT_ + rowb * 128 + ((64 + l4 * 16) ^ sw)); \
      _Pragma("unroll") \
      for (int eb = 0; eb < 4; ++eb) { \
        racc[eb][mb] = MFMA(va[eb][0], at0, racc[eb][mb], 0, 0, 0); \
        racc[eb][mb] = MFMA(va[eb][1], at1, racc[eb][mb], 0, 0, 0); \
      } \
    } \
  } while (0)
#define FENCE() do { \
    asm volatile("s_waitcnt vmcnt(8) lgkmcnt(0)" ::: "memory"); \
    __builtin_amdgcn_s_barrier(); \
    __builtin_amdgcn_sched_barrier(0); \
  } while (0)

  // ---- prologue: stage tiles 0,1; V(0); shb->LDS; QK(0) ----
  STAGE_PN(0, 0);
  STAGE_PN(64, 8192);
  ISSUE_V(0);
#pragma unroll
  for (int i = 0; i < 2; ++i) {
    int ii = i * 256 + t;
    *(float4*)(shs + ii * 4) = *(const float4*)(shbz + ii * 4);
  }
  __syncthreads();  // full drain: prologue stages + V(0) complete
  QK_PHASE(0);
  FENCE();

  // ---- steady state: interval it runs PV(it) || QK(it+1) ----
  for (int it = 0; it < 31; ++it) {
    if (it < 30) STAGE_PN((it + 2) * 64, (it & 1) * 8192);
    __builtin_amdgcn_s_setprio(1);
    PV_PHASE(it);
    QK_PHASE(it + 1);
    __builtin_amdgcn_s_setprio(0);
    ISSUE_V((it + 1) * 64);
    FENCE();
  }
  // ---- epilogue phase ----
  PV_PHASE(31);

  csa0 += __shfl_xor(csa0, 16, 64);
  csa0 += __shfl_xor(csa0, 32, 64);
  csa1 += __shfl_xor(csa1, 16, 64);
  csa1 += __shfl_xor(csa1, 32, 64);
  if (l4 == 0) {
    cs_sm[wv * 32 + l15] = csa0;
    cs_sm[wv * 32 + 16 + l15] = csa1;
  }
  __syncthreads();  // full drain before smem reuse
  float invc[8];
#pragma unroll
  for (int mb = 0; mb < 8; ++mb) invc[mb] = 1.0f / (1e-9f + cs_sm[mb * 16 + l15]);
  const float* xb = p.x + (size_t)b * C_ * N_;
  char* Tr = smem;  // 64 m-rows x 256 e bf16 = 32KB per half
#pragma unroll
  for (int half = 0; half < 2; ++half) {
    if (half) __syncthreads();
#pragma unroll
    for (int eb = 0; eb < 4; ++eb)
#pragma unroll
      for (int mbh = 0; mbh < 4; ++mbh) {
        int mb = half * 4 + mbh;
        int e0 = wv * 64 + eb * 16 + l4 * 4;
        int m_l = mbh * 16 + l15;
        int mg = m0 + mb * 16 + l15;
        float v0 = xb[(size_t)(e0 + 0) * N_ + mg] - racc[eb][mb][0] * invc[mb];
        float v1 = xb[(size_t)(e0 + 1) * N_ + mg] - racc[eb][mb][1] * invc[mb];
        float v2 = xb[(size_t)(e0 + 2) * N_ + mg] - racc[eb][mb][2] * invc[mb];
        float v3 = xb[(size_t)(e0 + 3) * N_ + mg] - racc[eb][mb][3] * invc[mb];
        uint2 pk = { cvtpk(v0, v1), cvtpk(v2, v3) };
        *(uint2*)(Tr + m_l * 512 + ((e0 * 2) ^ ((m_l & 7) << 4))) = pk;
      }
    __syncthreads();
    short* xz = p.xmr + ((size_t)z * N_ + m0 + half * 64) * C_;
#pragma unroll
    for (int i = 0; i < 8; ++i) {
      int idx = i * 256 + t;
      int m_l = idx >> 5, off2 = (idx & 31) * 16;
      s8v v = *(const s8v*)(Tr + m_l * 512 + (off2 ^ ((m_l & 7) << 4)));
      *(s8v*)((char*)(xz + (size_t)m_l * C_) + off2) = v;
    }
  }
#undef STAGE_PN
#undef ISSUE_V
#undef QK_PHASE
#undef PV_PHASE
#undef FENCE
}

// MFMA GEMM, 128x128 tile, K=256, single-buffered gload_lds staging.
// EPI 1: V = w_v*x + b_v (fp16 inputs) -> Vb bf16 [z][C][N]
// EPI 3: HO = x + relu(bn(w_t*xmr^T + b_t)) (bf16) -> HOT [b][N][HC]
template<int EPI>
__global__ __launch_bounds__(256) void mm_k(GP p) {
  constexpr int K = 256;
  const int t = threadIdx.x;
  const int wave = t >> 6, lane = t & 63;
  const int wr = wave >> 1, wc = wave & 1;
  const int l15 = lane & 15, l4 = lane >> 4;
  const int n0 = blockIdx.x * 128;
  const int m0 = blockIdx.y * 128;
  const int z = blockIdx.z;
  int b = z / H_, h = z % H_;

  const short *Ag, *Bg;
  if constexpr (EPI == 1) {
    Ag = (const short*)(p.wvh + (size_t)h * C_ * C_);
    Bg = (const short*)(p.xT + (size_t)b * N_ * C_);
  } else {
    Ag = p.wtb + (size_t)h * C_ * C_;
    Bg = p.xmr + (size_t)z * N_ * C_;
  }

  __shared__ short As[128 * 32];
  __shared__ short Bs[128 * 32];

  f32x4 acc[4][4] = {};

  for (int k0 = 0; k0 < K; k0 += 32) {
    __syncthreads();
#pragma unroll
    for (int i = 0; i < 2; ++i) {
      int idx = i * 256 + t;
      int row = idx >> 2, kg = (idx & 3) * 8;
      gload16(Ag + (size_t)(m0 + row) * K + k0 + kg, (char*)As + idx * 16);
      gload16(Bg + (size_t)(n0 + row) * K + k0 + kg, (char*)Bs + idx * 16);
    }
    __syncthreads();
    s8v af[4], bf[4];
#pragma unroll
    for (int m = 0; m < 4; ++m) af[m] = *(const s8v*)&As[(wr * 64 + m * 16 + l15) * 32 + l4 * 8];
#pragma unroll
    for (int n = 0; n < 4; ++n) bf[n] = *(const s8v*)&Bs[(wc * 64 + n * 16 + l15) * 32 + l4 * 8];
#pragma unroll
    for (int m = 0; m < 4; ++m)
#pragma unroll
      for (int n = 0; n < 4; ++n) {
        if constexpr (EPI == 1)
          acc[m][n] = MFMAH(__builtin_bit_cast(h8v, af[m]), __builtin_bit_cast(h8v, bf[n]),
                            acc[m][n], 0, 0, 0);
        else
          acc[m][n] = MFMA(af[m], bf[n], acc[m][n], 0, 0, 0);
      }
  }

  if constexpr (EPI == 1) {
    short* Vz = p.Vb + (size_t)z * C_ * N_;
#pragma unroll
    for (int m = 0; m < 4; ++m)
#pragma unroll
      for (int r = 0; r < 4; ++r) {
        int e = m0 + wr * 64 + m * 16 + l4 * 4 + r;
        float bias = p.b_v[h * C_ + e];
#pragma unroll
        for (int n = 0; n < 4; ++n) {
          int c = n0 + wc * 64 + n * 16 + l15;
          Vz[(size_t)e * N_ + c] = (short)f2b(acc[m][n][r] + bias);
        }
      }
  } else {
    __shared__ short Tr[128 * 128];
    const float* xb = p.x + (size_t)b * C_ * N_;
#pragma unroll
    for (int m = 0; m < 4; ++m)
#pragma unroll
      for (int r = 0; r < 4; ++r) {
        int e = m0 + wr * 64 + m * 16 + l4 * 4 + r;
        int el = e - m0;
        int hc = h * C_ + e;
        float bt = p.b_t[hc], mm = p.bn_m[hc], bb = p.bn_b[hc];
        float sc = p.bn_g[hc] / sqrtf(p.bn_v[hc] + BN_EPS);
#pragma unroll
        for (int n = 0; n < 4; ++n) {
          int cl = wc * 64 + n * 16 + l15;
          float y = (acc[m][n][r] + bt - mm) * sc + bb;
          float val = xb[(size_t)e * N_ + n0 + cl] + fmaxf(y, 0.f);
          Tr[cl * 128 + el] = (short)f2b(val);
        }
      }
    __syncthreads();
    short* Hz = p.HOT + (size_t)b * N_ * HC_;
#pragma unroll
    for (int it = 0; it < 8; ++it) {
      int idx = it * 256 + t;
      int cl = idx >> 4, eg = (idx & 15) * 8;
      *(s8v*)(Hz + (size_t)(n0 + cl) * HC_ + h * C_ + m0 + eg) = *(const s8v*)&Tr[cl * 128 + eg];
    }
  }
}

// Final GEMM: out = leaky(bn(w_lin*HOT^T)), 64x128 tile, K=2048, BK=64 -> 256 blocks
__global__ __launch_bounds__(256, 2) void mm4_k(GP p) {
  const int t = threadIdx.x, wv = t >> 6, lane = t & 63;
  const int l15 = lane & 15, l4 = lane >> 4;
  const int n0 = blockIdx.x * 128;
  const int m0 = blockIdx.y * 64;
  const int b = blockIdx.z;
  const short* Ag = p.wlinb;
  const short* Bg = p.HOT + (size_t)b * N_ * HC_;
  __shared__ short As[64 * 64], Bs[128 * 64];
  f32x4 acc[4][2] = {};
  for (int k0 = 0; k0 < HC_; k0 += 64) {
    __syncthreads();
#pragma unroll
    for (int i = 0; i < 2; ++i) {
      int sl = i * 256 + t;
      int rw = sl >> 3, of = (sl & 7) * 16;
      gload16((const char*)(Ag + (size_t)(m0 + rw) * HC_ + k0) + (of ^ ((rw & 7) << 4)),
              (char*)As + sl * 16);
    }
#pragma unroll
    for (int i = 0; i < 4; ++i) {
      int sl = i * 256 + t;
      int rw = sl >> 3, of = (sl & 7) * 16;
      gload16((const char*)(Bg + (size_t)(n0 + rw) * HC_ + k0) + (of ^ ((rw & 7) << 4)),
              (char*)Bs + sl * 16);
    }
    __syncthreads();
    s8v af[4][2], bf[2][2];
#pragma unroll
    for (int m = 0; m < 4; ++m)
#pragma unroll
      for (int ks = 0; ks < 2; ++ks) {
        int rw = m * 16 + l15;
        af[m][ks] = *(const s8v*)((const char*)As + rw * 128 + ((ks * 64 + l4 * 16) ^ ((rw & 7) << 4)));
      }
#pragma unroll
    for (int nf = 0; nf < 2; ++nf)
#pragma unroll
      for (int ks = 0; ks < 2; ++ks) {
        int rw = wv * 32 + nf * 16 + l15;
        bf[nf][ks] = *(const s8v*)((const char*)Bs + rw * 128 + ((ks * 64 + l4 * 16) ^ ((rw & 7) << 4)));
      }
#pragma unroll
    for (int m = 0; m < 4; ++m)
#pragma unroll
      for (int nf = 0; nf < 2; ++nf) {
        acc[m][nf] = MFMA(af[m][0], bf[nf][0], acc[m][nf], 0, 0, 0);
        acc[m][nf] = MFMA(af[m][1], bf[nf][1], acc[m][nf], 0, 0, 0);
      }
  }
  float* ob = p.out + (size_t)b * C_ * N_;
#pragma unroll
  for (int m = 0; m < 4; ++m)
#pragma unroll
    for (int r = 0; r < 4; ++r) {
      int e = m0 + m * 16 + l4 * 4 + r;
      float mm = p.lbn_m[e], bb = p.lbn_b[e];
      float sc = p.lbn_g[e] / sqrtf(p.lbn_v[e] + BN_EPS);
#pragma unroll
      for (int nf = 0; nf < 2; ++nf) {
        int c = n0 + wv * 32 + nf * 16 + l15;
        float y = (acc[m][nf][r] - mm) * sc + bb;
        ob[(size_t)e * N_ + c] = y >= 0.f ? y : 0.2f * y;
      }
    }
}

extern "C" void kernel_launch(void* const* d_in, const int* in_sizes, int n_in,
                              void* d_out, int out_size, void* d_ws, size_t ws_size,
                              hipStream_t stream) {
  GP p;
  p.x     = (const float*)d_in[0];
  p.w_qk  = (const float*)d_in[1];
  p.w_v   = (const float*)d_in[2];
  p.b_v   = (const float*)d_in[3];
  p.w_t   = (const float*)d_in[4];
  p.b_t   = (const float*)d_in[5];
  p.bn_g  = (const float*)d_in[6];
  p.bn_b  = (const float*)d_in[7];
  p.bn_m  = (const float*)d_in[8];
  p.bn_v  = (const float*)d_in[9];
  p.w_lin = (const float*)d_in[10];
  p.lbn_g = (const float*)d_in[11];
  p.lbn_b = (const float*)d_in[12];
  p.lbn_m = (const float*)d_in[13];
  p.lbn_v = (const float*)d_in[14];
  p.out   = (float*)d_out;

  char* base = (char*)d_ws;
  size_t off = 0;
  auto alloc = [&](size_t bytes) -> char* {
    char* r = base + off;
    off += (bytes + 255) & ~(size_t)255;
    return r;
  };
  p.PT    = (_Float16*)alloc((size_t)BH_ * N_ * D_ * 2);
  p.xT    = (_Float16*)alloc((size_t)B_ * N_ * C_ * 2);
  p.wqk16 = (_Float16*)alloc((size_t)H_ * D_ * C_ * 2);
  p.wvh   = (_Float16*)alloc((size_t)H_ * C_ * C_ * 2);
  p.wtb   = (short*)alloc((size_t)H_ * C_ * C_ * 2);
  p.wlinb = (short*)alloc((size_t)C_ * HC_ * 2);
  p.Vb    = (short*)alloc((size_t)BH_ * C_ * N_ * 2);
  p.xmr   = (short*)alloc((size_t)BH_ * N_ * C_ * 2);
  p.part  = (float*)alloc((size_t)BH_ * 16 * N_ * 4);
  p.shb   = (float*)alloc((size_t)BH_ * N_ * 4);
  p.nrm   = (float*)alloc((size_t)BH_ * N_ * 4);
  p.sh    = (float*)alloc((size_t)BH_ * N_ * 4);
  p.HOT   = p.Vb;  // alias: Vb dead after passb_k, HOT same size (32 MB)

  dim3 blk(256);

  prep_k<<<1664, blk, 0, stream>>>(p);
  xcvt_k<<<dim3(32, 4, B_), blk, 0, stream>>>(p.x, p.xT);
  p_k<<<dim3(16, BH_), blk, 0, stream>>>(p);
  shift_k<<<BH_, blk, 0, stream>>>(p.nrm, p.sh);
  mm_k<1><<<dim3(16, 2, BH_), blk, 0, stream>>>(p);
  passa_k<<<dim3(32, 136), blk, 0, stream>>>(p);
  shbred_k<<<256, blk, 0, stream>>>(p.part, p.sh, p.shb);
  passb_k<<<dim3(32, 16), blk, 0, stream>>>(p);
  mm_k<3><<<dim3(16, 2, BH_), blk, 0, stream>>>(p);
  mm4_k<<<dim3(16, 4, B_), blk, 0, stream>>>(p);
}

// Round 18
// 220.068 us; speedup vs baseline: 1.0188x; 1.0188x over previous
//
#include <hip/hip_runtime.h>
#include <math.h>

#define B_ 4
#define C_ 256
#define N_ 2048
#define H_ 8
#define D_ 64
#define BH_ 32
#define HC_ 2048
#define BN_EPS 1e-5f
#define SCL 1.2011224087864498f  // sqrt(log2(e)); P scaled so E' = log2(e)*E

typedef __attribute__((ext_vector_type(8))) short s8v;
typedef __attribute__((ext_vector_type(4))) short s4v;
typedef __attribute__((ext_vector_type(8))) _Float16 h8v;
typedef __attribute__((ext_vector_type(4))) _Float16 h4v;
typedef __attribute__((ext_vector_type(4))) float f32x4;

#define MFMA __builtin_amdgcn_mfma_f32_16x16x32_bf16
#define MFMAH __builtin_amdgcn_mfma_f32_16x16x32_f16

static __device__ __forceinline__ unsigned short f2b(float f) {
  union { float f; unsigned int i; } v; v.f = f;
  unsigned int r = v.i + 0x7FFFu + ((v.i >> 16) & 1u);
  return (unsigned short)(r >> 16);
}
static __device__ __forceinline__ float fexp2(float x) {
  float r;
  asm("v_exp_f32 %0, %1" : "=v"(r) : "v"(x));
  return r;
}
static __device__ __forceinline__ unsigned cvtpk(float lo, float hi) {
  unsigned r;
  asm("v_cvt_pk_bf16_f32 %0, %1, %2" : "=v"(r) : "v"(lo), "v"(hi));
  return r;
}
static __device__ __forceinline__ void gload16(const void* g, void* l) {
  __builtin_amdgcn_global_load_lds(
      (const __attribute__((address_space(1))) unsigned int*)g,
      (__attribute__((address_space(3))) unsigned int*)l, 16, 0, 0);
}

struct GP {
  const float *x, *w_qk, *w_v, *b_v, *w_t, *b_t, *bn_g, *bn_b, *bn_m, *bn_v;
  const float *w_lin, *lbn_g, *lbn_b, *lbn_m, *lbn_v;
  _Float16 *PT, *xT, *wqk16, *wvh;
  short *HOT, *wtb, *wlinb, *Vb, *xmr;
  float *part, *shb, *nrm, *sh, *out;
};

// fused weight conversions: w_t->bf16, w_lin->bf16, w_v->fp16, w_qk->fp16
__global__ __launch_bounds__(256) void prep_k(GP p) {
  int u = blockIdx.x * 256 + threadIdx.x;
  if (u < 131072) {
    int i = u * 4;
    float4 v = *(const float4*)(p.w_t + i);
    s4v o = { (short)f2b(v.x), (short)f2b(v.y), (short)f2b(v.z), (short)f2b(v.w) };
    *(s4v*)(p.wtb + i) = o;
  } else if (u < 262144) {
    int i = (u - 131072) * 4;
    float4 v = *(const float4*)(p.w_lin + i);
    s4v o = { (short)f2b(v.x), (short)f2b(v.y), (short)f2b(v.z), (short)f2b(v.w) };
    *(s4v*)(p.wlinb + i) = o;
  } else if (u < 393216) {
    int i = (u - 262144) * 4;
    float4 v = *(const float4*)(p.w_v + i);
    h4v o = { (_Float16)v.x, (_Float16)v.y, (_Float16)v.z, (_Float16)v.w };
    *(h4v*)(p.wvh + i) = o;
  } else {
    int i = (u - 393216) * 4;
    float4 v = *(const float4*)(p.w_qk + i);
    h4v o = { (_Float16)v.x, (_Float16)v.y, (_Float16)v.z, (_Float16)v.w };
    *(h4v*)(p.wqk16 + i) = o;
  }
}

// x [B][C][N] fp32 -> xT [B][N][C] fp16
__global__ __launch_bounds__(256) void xcvt_k(const float* __restrict__ x,
                                              _Float16* __restrict__ xT) {
  const int n0 = blockIdx.x * 64, c0 = blockIdx.y * 64, b = blockIdx.z;
  const float* xb = x + (size_t)b * C_ * N_;
  __shared__ float sm[64][65];
  const int t = threadIdx.x;
#pragma unroll
  for (int i = 0; i < 4; ++i) {
    int idx = i * 256 + t;
    int c = idx >> 4, j = (idx & 15) * 4;
    float4 v = *(const float4*)(xb + (size_t)(c0 + c) * N_ + n0 + j);
    sm[j + 0][c] = v.x; sm[j + 1][c] = v.y; sm[j + 2][c] = v.z; sm[j + 3][c] = v.w;
  }
  __syncthreads();
#pragma unroll
  for (int i = 0; i < 2; ++i) {
    int idx = i * 256 + t;
    int n = idx >> 3, cg = (idx & 7) * 8;
    h8v o;
#pragma unroll
    for (int d = 0; d < 8; ++d) o[d] = (_Float16)sm[n][cg + d];
    *(h8v*)(xT + ((size_t)b * N_ + n0 + n) * C_ + c0 + cg) = o;
  }
}

// P = w_qk*x fp16 MFMA; writes SCALED fp16 PT [bh][N][D] + row sumsq nrm
__global__ __launch_bounds__(256, 2) void p_k(GP p) {
  const int t = threadIdx.x, wv = t >> 6, lane = t & 63;
  const int l15 = lane & 15, l4 = lane >> 4;
  const int n0 = blockIdx.x * 128;
  const int bh = blockIdx.y, b = bh / H_, h = bh % H_;
  const _Float16* Ag = p.wqk16 + h * D_ * C_;
  const _Float16* Bg = p.xT + (size_t)b * N_ * C_;
  __shared__ _Float16 As[64 * 64], Bs[128 * 64];
  __shared__ float Tr[128 * 65];
  f32x4 acc[4][2] = {};
  for (int kc = 0; kc < 256; kc += 64) {
    __syncthreads();
#pragma unroll
    for (int i = 0; i < 2; ++i) {
      int idx = i * 256 + t;
      int row = idx >> 3, offl = (idx & 7) * 16;
      gload16((const char*)(Ag + (size_t)row * C_ + kc) + (offl ^ ((row & 7) << 4)),
              (char*)As + idx * 16);
    }
#pragma unroll
    for (int i = 0; i < 4; ++i) {
      int idx = i * 256 + t;
      int row = idx >> 3, offl = (idx & 7) * 16;
      gload16((const char*)(Bg + (size_t)(n0 + row) * C_ + kc) + (offl ^ ((row & 7) << 4)),
              (char*)Bs + idx * 16);
    }
    __syncthreads();
    h8v ad[4][2], bn[2][2];
#pragma unroll
    for (int d = 0; d < 4; ++d)
#pragma unroll
      for (int ks = 0; ks < 2; ++ks) {
        int row = d * 16 + l15;
        ad[d][ks] = *(const h8v*)((const char*)As + row * 128 + ((ks * 64 + l4 * 16) ^ ((row & 7) << 4)));
      }
#pragma unroll
    for (int nb = 0; nb < 2; ++nb)
#pragma unroll
      for (int ks = 0; ks < 2; ++ks) {
        int row = wv * 32 + nb * 16 + l15;
        bn[nb][ks] = *(const h8v*)((const char*)Bs + row * 128 + ((ks * 64 + l4 * 16) ^ ((row & 7) << 4)));
      }
#pragma unroll
    for (int d = 0; d < 4; ++d)
#pragma unroll
      for (int nb = 0; nb < 2; ++nb) {
        acc[d][nb] = MFMAH(ad[d][0], bn[nb][0], acc[d][nb], 0, 0, 0);
        acc[d][nb] = MFMAH(ad[d][1], bn[nb][1], acc[d][nb], 0, 0, 0);
      }
  }
  __syncthreads();
#pragma unroll
  for (int d = 0; d < 4; ++d)
#pragma unroll
    for (int nb = 0; nb < 2; ++nb)
#pragma unroll
      for (int r = 0; r < 4; ++r) {
        int n_l = wv * 32 + nb * 16 + l15;
        int dd = d * 16 + l4 * 4 + r;
        Tr[n_l * 65 + dd] = acc[d][nb][r];
      }
  __syncthreads();
  _Float16* Pf = p.PT + ((size_t)bh * N_ + n0) * D_;
  float* nz = p.nrm + (size_t)bh * N_;
#pragma unroll
  for (int i = 0; i < 4; ++i) {
    int idx = i * 256 + t;
    int n = idx >> 3, dg = (idx & 7) * 8;
    h8v hv;
    float ssq = 0.f;
#pragma unroll
    for (int j = 0; j < 8; ++j) {
      float v = Tr[n * 65 + dg + j] * SCL;
      ssq = fmaf(v, v, ssq);
      hv[j] = (_Float16)v;
    }
    *(h8v*)(Pf + (size_t)n * D_ + dg) = hv;
    ssq += __shfl_xor(ssq, 1, 64);
    ssq += __shfl_xor(ssq, 2, 64);
    ssq += __shfl_xor(ssq, 4, 64);
    if ((t & 7) == 0) nz[n0 + n] = ssq;
  }
}

// per z: M' = max ||P'||; sh[n] = ||P'_n|| * M'  (upper bound on E' row max)
__global__ __launch_bounds__(256) void shift_k(const float* __restrict__ nrm,
                                               float* __restrict__ sh) {
  const int z = blockIdx.x, t = threadIdx.x;
  const float* nz = nrm + (size_t)z * N_;
  float loc[8];
  float mx = 0.f;
#pragma unroll
  for (int i = 0; i < 8; ++i) {
    loc[i] = nz[i * 256 + t];
    mx = fmaxf(mx, loc[i]);
  }
  for (int o = 32; o; o >>= 1) mx = fmaxf(mx, __shfl_xor(mx, o, 64));
  __shared__ float sb[4];
  if ((t & 63) == 0) sb[t >> 6] = mx;
  __syncthreads();
  float M = sqrtf(fmaxf(fmaxf(sb[0], sb[1]), fmaxf(sb[2], sb[3])));
#pragma unroll
  for (int i = 0; i < 8; ++i)
    sh[(size_t)z * N_ + i * 256 + t] = sqrtf(loc[i]) * M;
}

// pass A (symmetric, shifted, fp16): upper-tri 128x128 tiles, exp2(E'-sh) row+col sums
__global__ __launch_bounds__(256, 4) void passa_k(GP p) {
  const int t = threadIdx.x, wv = t >> 6, lane = t & 63;
  const int l15 = lane & 15, l4 = lane >> 4;
  const int wr = wv >> 1, wc = wv & 1;
  const int z = blockIdx.x;
  int idx = blockIdx.y;
  int ti = 0;
  while (idx >= 16 - ti) { idx -= 16 - ti; ++ti; }
  const int tj = ti + idx;
  const int r0 = ti * 128, c0 = tj * 128;
  const _Float16* Pz = p.PT + (size_t)z * N_ * D_;
  const float* shz = p.sh + (size_t)z * N_;
  __shared__ short RH[8192], CH[8192];
  __shared__ float rbuf[2][2][64], cbuf[2][2][64];
#pragma unroll
  for (int i = 0; i < 4; ++i) {
    int c2 = i * 256 + t;
    int row = c2 >> 3, offl = (c2 & 7) * 16;
    int so = offl ^ ((row & 7) << 4);
    gload16((const char*)(Pz + (size_t)(r0 + row) * D_) + so, (char*)RH + c2 * 16);
    if (ti != tj)
      gload16((const char*)(Pz + (size_t)(c0 + row) * D_) + so, (char*)CH + c2 * 16);
  }
  __syncthreads();
  const char* BHp = (ti == tj) ? (const char*)RH : (const char*)CH;

  h8v bh4[4][2];
  float shc[4];
#pragma unroll
  for (int nf = 0; nf < 4; ++nf) {
#pragma unroll
    for (int ks = 0; ks < 2; ++ks) {
      int row = wc * 64 + nf * 16 + l15;
      int byte = row * 128 + ((ks * 64 + l4 * 16) ^ ((row & 7) << 4));
      bh4[nf][ks] = *(const h8v*)(BHp + byte);
    }
    shc[nf] = shz[c0 + wc * 64 + nf * 16 + l15];
  }
  float rowp[4][4] = {};
  float colp[4] = {};
#pragma unroll
  for (int mf = 0; mf < 4; ++mf) {
    h8v ah[2];
#pragma unroll
    for (int ks = 0; ks < 2; ++ks) {
      int row = wr * 64 + mf * 16 + l15;
      int byte = row * 128 + ((ks * 64 + l4 * 16) ^ ((row & 7) << 4));
      ah[ks] = *(const h8v*)((const char*)RH + byte);
    }
    f32x4 shr = *(const f32x4*)(shz + r0 + wr * 64 + mf * 16 + l4 * 4);
#pragma unroll
    for (int nf = 0; nf < 4; ++nf) {
      f32x4 s = {};
      s = MFMAH(ah[0], bh4[nf][0], s, 0, 0, 0);
      s = MFMAH(ah[1], bh4[nf][1], s, 0, 0, 0);
      rowp[mf][0] += fexp2(s[0] - shr[0]);
      rowp[mf][1] += fexp2(s[1] - shr[1]);
      rowp[mf][2] += fexp2(s[2] - shr[2]);
      rowp[mf][3] += fexp2(s[3] - shr[3]);
      if (ti != tj)
        colp[nf] += fexp2(s[0] - shc[nf]) + fexp2(s[1] - shc[nf]) +
                    fexp2(s[2] - shc[nf]) + fexp2(s[3] - shc[nf]);
    }
  }
#pragma unroll
  for (int mf = 0; mf < 4; ++mf)
#pragma unroll
    for (int r = 0; r < 4; ++r) {
      float v = rowp[mf][r];
      v += __shfl_xor(v, 1, 64); v += __shfl_xor(v, 2, 64);
      v += __shfl_xor(v, 4, 64); v += __shfl_xor(v, 8, 64);
      rowp[mf][r] = v;
    }
#pragma unroll
  for (int nf = 0; nf < 4; ++nf) {
    float v = colp[nf];
    v += __shfl_xor(v, 16, 64); v += __shfl_xor(v, 32, 64);
    colp[nf] = v;
  }
  if (l15 == 0)
#pragma unroll
    for (int mf = 0; mf < 4; ++mf)
#pragma unroll
      for (int r = 0; r < 4; ++r)
        rbuf[wr][wc][mf * 16 + l4 * 4 + r] = rowp[mf][r];
  if (l4 == 0)
#pragma unroll
    for (int nf = 0; nf < 4; ++nf)
      cbuf[wc][wr][nf * 16 + l15] = colp[nf];
  __syncthreads();
  if (t < 128) {
    float v = rbuf[t >> 6][0][t & 63] + rbuf[t >> 6][1][t & 63];
    p.part[((size_t)z * 16 + tj) * N_ + r0 + t] = v;
  } else if (ti != tj) {
    int u = t - 128;
    float v = cbuf[u >> 6][0][u & 63] + cbuf[u >> 6][1][u & 63];
    p.part[((size_t)z * 16 + ti) * N_ + c0 + u] = v;
  }
}

// shb[z][n] = sh[z][n] + log2( sum_j part[z][j][n] )
__global__ __launch_bounds__(256) void shbred_k(const float* __restrict__ part,
                                                const float* __restrict__ sh,
                                                float* __restrict__ shb) {
  int i = blockIdx.x * 256 + threadIdx.x;
  int z = i >> 11, n = i & 2047;
  const float* pz = part + ((size_t)z * 16) * N_ + n;
  float s = 0.f;
#pragma unroll
  for (int j = 0; j < 16; ++j) s += pz[(size_t)j * N_];
  shb[i] = sh[i] + __log2f(s);
}

// pass B: fused exp2(s - shb) + PV + colsum renorm; 128-wide m tile
// (best measured config: (256,2), double-AT, 1 barrier/iter, counted vmcnt)
__global__ __launch_bounds__(256, 2) void passb_k(GP p) {
  const int t = threadIdx.x, wv = t >> 6, lane = t & 63;
  const int l15 = lane & 15, l4 = lane >> 4;
  const int z = blockIdx.x, b = z / H_;
  const int m0 = blockIdx.y * 128;
  const _Float16* Pz = p.PT + (size_t)z * N_ * D_;
  const short* Vz = p.Vb + (size_t)z * C_ * N_;
  const float* shbz = p.shb + (size_t)z * N_;

  __shared__ char smem[57856];
  // [0,16384): Pn[2] 8192B; [16384,49152): AT[2] 16384B; [49152,49664): cs; [49664,57856): shb
  float* cs_sm = (float*)(smem + 49152);
  float* shs = (float*)(smem + 49664);

  // B-operand (Pm): 2 fragments per wave
  h8v bm[2][2];
#pragma unroll
  for (int mf = 0; mf < 2; ++mf)
#pragma unroll
    for (int ks = 0; ks < 2; ++ks)
      bm[mf][ks] = *(const h8v*)(Pz + (size_t)(m0 + wv * 32 + mf * 16 + l15) * D_ + ks * 32 + l4 * 8);

  s8v va[4][2];

#define STAGE_PN(n0v, bufbyte) do { \
    _Pragma("unroll") \
    for (int i_ = 0; i_ < 2; ++i_) { \
      int sl_ = i_ * 256 + t; \
      int rw_ = sl_ >> 3, of_ = (sl_ & 7) * 16; \
      gload16((const char*)(Pz + (size_t)((n0v) + rw_) * D_) + (of_ ^ ((rw_ & 7) << 4)), \
              smem + (bufbyte) + sl_ * 16); \
    } \
  } while (0)
#define ISSUE_V(n0v) do { \
    _Pragma("unroll") \
    for (int eb = 0; eb < 4; ++eb) { \
      const short* vr_ = Vz + (size_t)(wv * 64 + eb * 16 + l15) * N_ + (n0v) + l4 * 8; \
      va[eb][0] = *(const s8v*)vr_; \
      va[eb][1] = *(const s8v*)(vr_ + 32); \
    } \
  } while (0)

  f32x4 racc[4][8] = {};
  float csa0 = 0.f, csa1 = 0.f;

  STAGE_PN(0, 0);
  STAGE_PN(64, 8192);
  ISSUE_V(0);
#pragma unroll
  for (int i = 0; i < 2; ++i) {
    int ii = i * 256 + t;
    *(float4*)(shs + ii * 4) = *(const float4*)(shbz + ii * 4);
  }
  __syncthreads();  // full drain: prologue stages complete

  for (int it = 0; it < 32; ++it) {
    const int n0 = it * 64;
    const int cur = it & 1;
    const char* PH = smem + cur * 8192;
    char* AT = smem + 16384 + cur * 16384;
    // ---- QK phase: E' tile + exp2(s - shb) -> AT (64 n x 128 m bf16) ----
#pragma unroll
    for (int nb = 0; nb < 4; ++nb) {
      int rowb = nb * 16 + l15;
      int sw = (rowb & 7) << 4;
      h8v an0 = *(const h8v*)(PH + rowb * 128 + ((l4 * 16) ^ sw));
      h8v an1 = *(const h8v*)(PH + rowb * 128 + ((64 + l4 * 16) ^ sw));
      f32x4 s0 = {}, s1 = {};
      s0 = MFMAH(an0, bm[0][0], s0, 0, 0, 0);
      s0 = MFMAH(an1, bm[0][1], s0, 0, 0, 0);
      s1 = MFMAH(an0, bm[1][0], s1, 0, 0, 0);
      s1 = MFMAH(an1, bm[1][1], s1, 0, 0, 0);
      f32x4 sb4 = *(const f32x4*)(shs + n0 + nb * 16 + l4 * 4);
      float a0 = fexp2(s0[0] - sb4[0]);
      float a1 = fexp2(s0[1] - sb4[1]);
      float a2 = fexp2(s0[2] - sb4[2]);
      float a3 = fexp2(s0[3] - sb4[3]);
      float c0 = fexp2(s1[0] - sb4[0]);
      float c1 = fexp2(s1[1] - sb4[1]);
      float c2 = fexp2(s1[2] - sb4[2]);
      float c3 = fexp2(s1[3] - sb4[3]);
      csa0 += (a0 + a1) + (a2 + a3);
      csa1 += (c0 + c1) + (c2 + c3);
      uint2 pk0 = { cvtpk(a0, a1), cvtpk(a2, a3) };
      uint2 pk1 = { cvtpk(c0, c1), cvtpk(c2, c3) };
      int swm = (l15 & 7) << 4;
      int cb = (nb * 32 + l4 * 8);
      *(uint2*)(AT + (wv * 32 + l15) * 128 + (cb ^ swm)) = pk0;
      *(uint2*)(AT + (wv * 32 + 16 + l15) * 128 + (cb ^ swm)) = pk1;
    }
    // ---- fence: AT writes visible; stage(it+1) landed (8 newer V ops stay in flight) ----
    asm volatile("s_waitcnt vmcnt(8) lgkmcnt(0)" ::: "memory");
    __builtin_amdgcn_s_barrier();
    __builtin_amdgcn_sched_barrier(0);
    // ---- stage tile it+2 into buf[cur]: all waves past QK(it)'s reads ----
    if (it < 30) STAGE_PN(n0 + 128, cur * 8192);
    // ---- PV phase ----
    __builtin_amdgcn_s_setprio(1);
#pragma unroll
    for (int mb = 0; mb < 8; ++mb) {
      int rowb = mb * 16 + l15;
      int sw = (rowb & 7) << 4;
      s8v at0 = *(const s8v*)(AT + rowb * 128 + ((l4 * 16) ^ sw));
      s8v at1 = *(const s8v*)(AT + rowb * 128 + ((64 + l4 * 16) ^ sw));
#pragma unroll
      for (int eb = 0; eb < 4; ++eb) {
        racc[eb][mb] = MFMA(va[eb][0], at0, racc[eb][mb], 0, 0, 0);
        racc[eb][mb] = MFMA(va[eb][1], at1, racc[eb][mb], 0, 0, 0);
      }
    }
    __builtin_amdgcn_s_setprio(0);
    if (it < 31) ISSUE_V(n0 + 64);
  }

  csa0 += __shfl_xor(csa0, 16, 64);
  csa0 += __shfl_xor(csa0, 32, 64);
  csa1 += __shfl_xor(csa1, 16, 64);
  csa1 += __shfl_xor(csa1, 32, 64);
  if (l4 == 0) {
    cs_sm[wv * 32 + l15] = csa0;
    cs_sm[wv * 32 + 16 + l15] = csa1;
  }
  __syncthreads();  // full drain before smem reuse
  float invc[8];
#pragma unroll
  for (int mb = 0; mb < 8; ++mb) invc[mb] = 1.0f / (1e-9f + cs_sm[mb * 16 + l15]);
  const float* xb = p.x + (size_t)b * C_ * N_;
  char* Tr = smem;  // 64 m-rows x 256 e bf16 = 32KB per half
#pragma unroll
  for (int half = 0; half < 2; ++half) {
    if (half) __syncthreads();
#pragma unroll
    for (int eb = 0; eb < 4; ++eb)
#pragma unroll
      for (int mbh = 0; mbh < 4; ++mbh) {
        int mb = half * 4 + mbh;
        int e0 = wv * 64 + eb * 16 + l4 * 4;
        int m_l = mbh * 16 + l15;
        int mg = m0 + mb * 16 + l15;
        float v0 = xb[(size_t)(e0 + 0) * N_ + mg] - racc[eb][mb][0] * invc[mb];
        float v1 = xb[(size_t)(e0 + 1) * N_ + mg] - racc[eb][mb][1] * invc[mb];
        float v2 = xb[(size_t)(e0 + 2) * N_ + mg] - racc[eb][mb][2] * invc[mb];
        float v3 = xb[(size_t)(e0 + 3) * N_ + mg] - racc[eb][mb][3] * invc[mb];
        uint2 pk = { cvtpk(v0, v1), cvtpk(v2, v3) };
        *(uint2*)(Tr + m_l * 512 + ((e0 * 2) ^ ((m_l & 7) << 4))) = pk;
      }
    __syncthreads();
    short* xz = p.xmr + ((size_t)z * N_ + m0 + half * 64) * C_;
#pragma unroll
    for (int i = 0; i < 8; ++i) {
      int idx = i * 256 + t;
      int m_l = idx >> 5, off2 = (idx & 31) * 16;
      s8v v = *(const s8v*)(Tr + m_l * 512 + (off2 ^ ((m_l & 7) << 4)));
      *(s8v*)((char*)(xz + (size_t)m_l * C_) + off2) = v;
    }
  }
#undef STAGE_PN
#undef ISSUE_V
}

// MFMA GEMM, 128x128 tile, K=256, single-buffered gload_lds staging.
// EPI 1: V = w_v*x + b_v (fp16 inputs) -> Vb bf16 [z][C][N]
// EPI 3: HO = x + relu(bn(w_t*xmr^T + b_t)) (bf16) -> HOT [b][N][HC]
template<int EPI>
__global__ __launch_bounds__(256) void mm_k(GP p) {
  constexpr int K = 256;
  const int t = threadIdx.x;
  const int wave = t >> 6, lane = t & 63;
  const int wr = wave >> 1, wc = wave & 1;
  const int l15 = lane & 15, l4 = lane >> 4;
  const int n0 = blockIdx.x * 128;
  const int m0 = blockIdx.y * 128;
  const int z = blockIdx.z;
  int b = z / H_, h = z % H_;

  const short *Ag, *Bg;
  if constexpr (EPI == 1) {
    Ag = (const short*)(p.wvh + (size_t)h * C_ * C_);
    Bg = (const short*)(p.xT + (size_t)b * N_ * C_);
  } else {
    Ag = p.wtb + (size_t)h * C_ * C_;
    Bg = p.xmr + (size_t)z * N_ * C_;
  }

  __shared__ short As[128 * 32];
  __shared__ short Bs[128 * 32];

  f32x4 acc[4][4] = {};

  for (int k0 = 0; k0 < K; k0 += 32) {
    __syncthreads();
#pragma unroll
    for (int i = 0; i < 2; ++i) {
      int idx = i * 256 + t;
      int row = idx >> 2, kg = (idx & 3) * 8;
      gload16(Ag + (size_t)(m0 + row) * K + k0 + kg, (char*)As + idx * 16);
      gload16(Bg + (size_t)(n0 + row) * K + k0 + kg, (char*)Bs + idx * 16);
    }
    __syncthreads();
    s8v af[4], bf[4];
#pragma unroll
    for (int m = 0; m < 4; ++m) af[m] = *(const s8v*)&As[(wr * 64 + m * 16 + l15) * 32 + l4 * 8];
#pragma unroll
    for (int n = 0; n < 4; ++n) bf[n] = *(const s8v*)&Bs[(wc * 64 + n * 16 + l15) * 32 + l4 * 8];
#pragma unroll
    for (int m = 0; m < 4; ++m)
#pragma unroll
      for (int n = 0; n < 4; ++n) {
        if constexpr (EPI == 1)
          acc[m][n] = MFMAH(__builtin_bit_cast(h8v, af[m]), __builtin_bit_cast(h8v, bf[n]),
                            acc[m][n], 0, 0, 0);
        else
          acc[m][n] = MFMA(af[m], bf[n], acc[m][n], 0, 0, 0);
      }
  }

  if constexpr (EPI == 1) {
    short* Vz = p.Vb + (size_t)z * C_ * N_;
#pragma unroll
    for (int m = 0; m < 4; ++m)
#pragma unroll
      for (int r = 0; r < 4; ++r) {
        int e = m0 + wr * 64 + m * 16 + l4 * 4 + r;
        float bias = p.b_v[h * C_ + e];
#pragma unroll
        for (int n = 0; n < 4; ++n) {
          int c = n0 + wc * 64 + n * 16 + l15;
          Vz[(size_t)e * N_ + c] = (short)f2b(acc[m][n][r] + bias);
        }
      }
  } else {
    __shared__ short Tr[128 * 128];
    const float* xb = p.x + (size_t)b * C_ * N_;
#pragma unroll
    for (int m = 0; m < 4; ++m)
#pragma unroll
      for (int r = 0; r < 4; ++r) {
        int e = m0 + wr * 64 + m * 16 + l4 * 4 + r;
        int el = e - m0;
        int hc = h * C_ + e;
        float bt = p.b_t[hc], mm = p.bn_m[hc], bb = p.bn_b[hc];
        float sc = p.bn_g[hc] / sqrtf(p.bn_v[hc] + BN_EPS);
#pragma unroll
        for (int n = 0; n < 4; ++n) {
          int cl = wc * 64 + n * 16 + l15;
          float y = (acc[m][n][r] + bt - mm) * sc + bb;
          float val = xb[(size_t)e * N_ + n0 + cl] + fmaxf(y, 0.f);
          Tr[cl * 128 + el] = (short)f2b(val);
        }
      }
    __syncthreads();
    short* Hz = p.HOT + (size_t)b * N_ * HC_;
#pragma unroll
    for (int it = 0; it < 8; ++it) {
      int idx = it * 256 + t;
      int cl = idx >> 4, eg = (idx & 15) * 8;
      *(s8v*)(Hz + (size_t)(n0 + cl) * HC_ + h * C_ + m0 + eg) = *(const s8v*)&Tr[cl * 128 + eg];
    }
  }
}

// Final GEMM: out = leaky(bn(w_lin*HOT^T)), 64x128 tile, K=2048, BK=64 -> 256 blocks
__global__ __launch_bounds__(256, 2) void mm4_k(GP p) {
  const int t = threadIdx.x, wv = t >> 6, lane = t & 63;
  const int l15 = lane & 15, l4 = lane >> 4;
  const int n0 = blockIdx.x * 128;
  const int m0 = blockIdx.y * 64;
  const int b = blockIdx.z;
  const short* Ag = p.wlinb;
  const short* Bg = p.HOT + (size_t)b * N_ * HC_;
  __shared__ short As[64 * 64], Bs[128 * 64];
  f32x4 acc[4][2] = {};
  for (int k0 = 0; k0 < HC_; k0 += 64) {
    __syncthreads();
#pragma unroll
    for (int i = 0; i < 2; ++i) {
      int sl = i * 256 + t;
      int rw = sl >> 3, of = (sl & 7) * 16;
      gload16((const char*)(Ag + (size_t)(m0 + rw) * HC_ + k0) + (of ^ ((rw & 7) << 4)),
              (char*)As + sl * 16);
    }
#pragma unroll
    for (int i = 0; i < 4; ++i) {
      int sl = i * 256 + t;
      int rw = sl >> 3, of = (sl & 7) * 16;
      gload16((const char*)(Bg + (size_t)(n0 + rw) * HC_ + k0) + (of ^ ((rw & 7) << 4)),
              (char*)Bs + sl * 16);
    }
    __syncthreads();
    s8v af[4][2], bf[2][2];
#pragma unroll
    for (int m = 0; m < 4; ++m)
#pragma unroll
      for (int ks = 0; ks < 2; ++ks) {
        int rw = m * 16 + l15;
        af[m][ks] = *(const s8v*)((const char*)As + rw * 128 + ((ks * 64 + l4 * 16) ^ ((rw & 7) << 4)));
      }
#pragma unroll
    for (int nf = 0; nf < 2; ++nf)
#pragma unroll
      for (int ks = 0; ks < 2; ++ks) {
        int rw = wv * 32 + nf * 16 + l15;
        bf[nf][ks] = *(const s8v*)((const char*)Bs + rw * 128 + ((ks * 64 + l4 * 16) ^ ((rw & 7) << 4)));
      }
#pragma unroll
    for (int m = 0; m < 4; ++m)
#pragma unroll
      for (int nf = 0; nf < 2; ++nf) {
        acc[m][nf] = MFMA(af[m][0], bf[nf][0], acc[m][nf], 0, 0, 0);
        acc[m][nf] = MFMA(af[m][1], bf[nf][1], acc[m][nf], 0, 0, 0);
      }
  }
  float* ob = p.out + (size_t)b * C_ * N_;
#pragma unroll
  for (int m = 0; m < 4; ++m)
#pragma unroll
    for (int r = 0; r < 4; ++r) {
      int e = m0 + m * 16 + l4 * 4 + r;
      float mm = p.lbn_m[e], bb = p.lbn_b[e];
      float sc = p.lbn_g[e] / sqrtf(p.lbn_v[e] + BN_EPS);
#pragma unroll
      for (int nf = 0; nf < 2; ++nf) {
        int c = n0 + wv * 32 + nf * 16 + l15;
        float y = (acc[m][nf][r] - mm) * sc + bb;
        ob[(size_t)e * N_ + c] = y >= 0.f ? y : 0.2f * y;
      }
    }
}

extern "C" void kernel_launch(void* const* d_in, const int* in_sizes, int n_in,
                              void* d_out, int out_size, void* d_ws, size_t ws_size,
                              hipStream_t stream) {
  GP p;
  p.x     = (const float*)d_in[0];
  p.w_qk  = (const float*)d_in[1];
  p.w_v   = (const float*)d_in[2];
  p.b_v   = (const float*)d_in[3];
  p.w_t   = (const float*)d_in[4];
  p.b_t   = (const float*)d_in[5];
  p.bn_g  = (const float*)d_in[6];
  p.bn_b  = (const float*)d_in[7];
  p.bn_m  = (const float*)d_in[8];
  p.bn_v  = (const float*)d_in[9];
  p.w_lin = (const float*)d_in[10];
  p.lbn_g = (const float*)d_in[11];
  p.lbn_b = (const float*)d_in[12];
  p.lbn_m = (const float*)d_in[13];
  p.lbn_v = (const float*)d_in[14];
  p.out   = (float*)d_out;

  char* base = (char*)d_ws;
  size_t off = 0;
  auto alloc = [&](size_t bytes) -> char* {
    char* r = base + off;
    off += (bytes + 255) & ~(size_t)255;
    return r;
  };
  p.PT    = (_Float16*)alloc((size_t)BH_ * N_ * D_ * 2);
  p.xT    = (_Float16*)alloc((size_t)B_ * N_ * C_ * 2);
  p.wqk16 = (_Float16*)alloc((size_t)H_ * D_ * C_ * 2);
  p.wvh   = (_Float16*)alloc((size_t)H_ * C_ * C_ * 2);
  p.wtb   = (short*)alloc((size_t)H_ * C_ * C_ * 2);
  p.wlinb = (short*)alloc((size_t)C_ * HC_ * 2);
  p.Vb    = (short*)alloc((size_t)BH_ * C_ * N_ * 2);
  p.xmr   = (short*)alloc((size_t)BH_ * N_ * C_ * 2);
  p.part  = (float*)alloc((size_t)BH_ * 16 * N_ * 4);
  p.shb   = (float*)alloc((size_t)BH_ * N_ * 4);
  p.nrm   = (float*)alloc((size_t)BH_ * N_ * 4);
  p.sh    = (float*)alloc((size_t)BH_ * N_ * 4);
  p.HOT   = p.Vb;  // alias: Vb dead after passb_k, HOT same size (32 MB)

  dim3 blk(256);

  prep_k<<<1664, blk, 0, stream>>>(p);
  xcvt_k<<<dim3(32, 4, B_), blk, 0, stream>>>(p.x, p.xT);
  p_k<<<dim3(16, BH_), blk, 0, stream>>>(p);
  shift_k<<<BH_, blk, 0, stream>>>(p.nrm, p.sh);
  mm_k<1><<<dim3(16, 2, BH_), blk, 0, stream>>>(p);
  passa_k<<<dim3(32, 136), blk, 0, stream>>>(p);
  shbred_k<<<256, blk, 0, stream>>>(p.part, p.sh, p.shb);
  passb_k<<<dim3(32, 16), blk, 0, stream>>>(p);
  mm_k<3><<<dim3(16, 2, BH_), blk, 0, stream>>>(p);
  mm4_k<<<dim3(16, 4, B_), blk, 0, stream>>>(p);
}